// Round 1
// baseline (577.131 us; speedup 1.0000x reference)
//
#include <hip/hip_runtime.h>

// Problem constants
#define BB 256
#define PP 128
#define CC 2
#define FF 7
#define KK 16
#define HH 128
#define OO 256
#define EE 18      // 2*(C+F)
#define XCH 10     // C + F + 1 (coords, feats, mask)
#define BIGD 1000000000.0f
#define GPT 4      // points per block in MLP kernel

// ---------------------------------------------------------------------------
// Kernel 1: exact KNN (top K+1 smallest dist2, stable ties by lower index,
// drop the nearest = self). One block per batch, one thread per point.
// dist2 computed with explicit rn mul/add (no fma contraction) to match numpy.
// ---------------------------------------------------------------------------
__global__ __launch_bounds__(PP) void knn_kernel(const float* __restrict__ x,
                                                 int* __restrict__ idx_out) {
    const int b = blockIdx.x;
    const int i = threadIdx.x;
    __shared__ float cx[PP], cy[PP], vmask[PP];
    const float* xb = x + (size_t)b * PP * XCH;
    cx[i] = xb[i * XCH + 0];
    cy[i] = xb[i * XCH + 1];
    vmask[i] = xb[i * XCH + (XCH - 1)];
    __syncthreads();

    const float ci_x = cx[i], ci_y = cy[i];
    float dlist[KK + 1];
    int   ilist[KK + 1];
#pragma unroll
    for (int m = 0; m <= KK; ++m) { dlist[m] = 3.0e38f; ilist[m] = -1; }

    for (int j = 0; j < PP; ++j) {
        float dx = ci_x - cx[j];
        float dy = ci_y - cy[j];
        float d = __fadd_rn(__fmul_rn(dx, dx), __fmul_rn(dy, dy));
        if (!(vmask[j] > 0.0f)) d = BIGD;
        if (d < dlist[KK]) {
            // stable sorted insert (ascending dist; equal keys keep earlier j)
#pragma unroll
            for (int m = KK; m >= 1; --m) {
                if (d < dlist[m]) {
                    bool fromprev = d < dlist[m - 1];
                    dlist[m] = fromprev ? dlist[m - 1] : d;
                    ilist[m] = fromprev ? ilist[m - 1] : j;
                }
            }
            if (d < dlist[0]) { dlist[0] = d; ilist[0] = j; }
        }
    }

    int* op = idx_out + ((size_t)(b * PP + i)) * KK;
#pragma unroll
    for (int m = 1; m <= KK; ++m) op[m - 1] = ilist[m];
}

// ---------------------------------------------------------------------------
// Kernel 2: fused edge-MLP. One block = GPT(4) points = 64 edge rows.
// edges(64x18) -> h1(64x128) relu in LDS -> h2(64x256) relu in registers
// -> mean over K=16 -> out (x mask).
// 256 threads. GEMM2: thread (ty=tid/32, tx=tid%32) owns rows ty*8..+8,
// cols tx*8..+8 (64 fp32 accumulators).
// ---------------------------------------------------------------------------
__global__ __launch_bounds__(256) void mlp_kernel(const float* __restrict__ x,
                                                  const int* __restrict__ knn,
                                                  const float* __restrict__ W1,
                                                  const float* __restrict__ b1,
                                                  const float* __restrict__ W2,
                                                  const float* __restrict__ b2,
                                                  float* __restrict__ out) {
    __shared__ float sW1[EE][HH];            // 9.2 KB
    __shared__ float sb1[HH];
    __shared__ float sb2[OO];
    __shared__ float sedge[GPT * KK][EE + 1]; // 64 x 19, 4.9 KB
    __shared__ float sh1[GPT * KK][HH];       // 64 x 128, 32 KB
    __shared__ float spart[8][OO];            // 8 KB
    __shared__ float smask[GPT];

    const int tid = threadIdx.x;
    const int pbase = blockIdx.x * GPT;

    // stage W1 / b1 / b2
    for (int t = tid; t < EE * HH; t += 256) sW1[t / HH][t % HH] = W1[t];
    if (tid < HH) sb1[tid] = b1[tid];
    sb2[tid] = b2[tid];  // OO == 256 == blockDim

    // build edge rows: row = tid/4 (0..63), part = tid%4 handles ~5 channels
    {
        const int row = tid >> 2;
        const int part = tid & 3;
        const int g = row >> 4;       // point within block
        const int k = row & (KK - 1); // neighbor slot
        const int pglob = pbase + g;
        const int b = pglob >> 7;     // / PP
        const int i = pglob & (PP - 1);
        const float* xb = x + (size_t)b * PP * XCH;
        const int j = knn[(size_t)pglob * KK + k];
        const int clo = part * 5;
        const int chi = (clo + 5 < EE) ? clo + 5 : EE;
        for (int c = clo; c < chi; ++c) {
            float v;
            if (c < CC + FF) {
                v = xb[i * XCH + c];                 // center coords+feats
            } else {
                int cc = c - (CC + FF);              // x channel 0..8
                v = xb[j * XCH + cc] - xb[i * XCH + cc];  // neighbor diff
            }
            sedge[row][c] = v;
        }
        if (part == 0 && k == 0) smask[g] = xb[i * XCH + (XCH - 1)];
    }
    __syncthreads();

    // GEMM1: h1[64][128] = relu(edge @ W1 + b1)
    {
        const int col = tid & (HH - 1);
        const int rhalf = tid >> 7; // 0 or 1
        for (int rr = 0; rr < 32; ++rr) {
            const int row = rr * 2 + rhalf;
            float acc = sb1[col];
#pragma unroll
            for (int c = 0; c < EE; ++c) acc = fmaf(sedge[row][c], sW1[c][col], acc);
            sh1[row][col] = fmaxf(acc, 0.0f);
        }
    }
    __syncthreads();

    // GEMM2: 64x256x128, register-tiled 8x8 per thread, W2 streamed from L1/L2
    const int tx = tid & 31;   // cols tx*8 .. tx*8+7
    const int ty = tid >> 5;   // rows ty*8 .. ty*8+7
    float acc[8][8];
#pragma unroll
    for (int r = 0; r < 8; ++r)
#pragma unroll
        for (int c = 0; c < 8; ++c) acc[r][c] = 0.0f;

    const float* W2base = W2 + tx * 8;
#pragma unroll 4
    for (int k = 0; k < HH; ++k) {
        float a[8];
#pragma unroll
        for (int r = 0; r < 8; ++r) a[r] = sh1[ty * 8 + r][k];
        const float* w = W2base + k * OO;
        const float4 wlo = *(const float4*)(w);
        const float4 whi = *(const float4*)(w + 4);
        const float wv[8] = {wlo.x, wlo.y, wlo.z, wlo.w, whi.x, whi.y, whi.z, whi.w};
#pragma unroll
        for (int r = 0; r < 8; ++r)
#pragma unroll
            for (int c = 0; c < 8; ++c) acc[r][c] = fmaf(a[r], wv[c], acc[r][c]);
    }

    // relu(+b2) and partial K-sum over this thread's 8 rows (half a point)
#pragma unroll
    for (int c = 0; c < 8; ++c) {
        const float bc = sb2[tx * 8 + c];
        float s = 0.0f;
#pragma unroll
        for (int r = 0; r < 8; ++r) s += fmaxf(acc[r][c] + bc, 0.0f);
        spart[ty][tx * 8 + c] = s;
    }
    __syncthreads();

    // combine half-point partials, scale by 1/K and mask, append ones channel
    for (int o = tid; o < GPT * (OO + 1); o += 256) {
        const int g = o / (OO + 1);
        const int c = o % (OO + 1);
        const float m = smask[g];
        float v;
        if (c < OO) v = (spart[2 * g][c] + spart[2 * g + 1][c]) * (1.0f / KK);
        else        v = 1.0f;
        out[(size_t)(pbase + g) * (OO + 1) + c] = v * m;
    }
}

extern "C" void kernel_launch(void* const* d_in, const int* in_sizes, int n_in,
                              void* d_out, int out_size, void* d_ws, size_t ws_size,
                              hipStream_t stream) {
    const float* x  = (const float*)d_in[0];
    const float* W1 = (const float*)d_in[1];
    const float* b1 = (const float*)d_in[2];
    const float* W2 = (const float*)d_in[3];
    const float* b2 = (const float*)d_in[4];
    float* out = (float*)d_out;
    int* knn_idx = (int*)d_ws;   // B*P*K ints = 2 MB

    knn_kernel<<<BB, PP, 0, stream>>>(x, knn_idx);

    const int nblocks = (BB * PP) / GPT;  // 8192
    mlp_kernel<<<nblocks, 256, 0, stream>>>(x, knn_idx, W1, b1, W2, b2, out);
}

// Round 2
// 214.060 us; speedup vs baseline: 2.6961x; 2.6961x over previous
//
#include <hip/hip_runtime.h>

// Problem constants
#define BB 256
#define PP 128
#define CC 2
#define FF 7
#define KK 16
#define HH 128
#define OO 256
#define EE 18      // 2*(C+F)
#define XCH 10     // C + F + 1 (coords, feats, mask)
#define BIGD 1000000000.0f
#define GPT 4      // points per block in MLP kernel

typedef __bf16 bf16x8 __attribute__((ext_vector_type(8)));
typedef __bf16 bf16x2 __attribute__((ext_vector_type(2)));
typedef float  f32x4  __attribute__((ext_vector_type(4)));

// ---------------------------------------------------------------------------
// Kernel 1: exact KNN (top K+1 smallest dist2, stable ties by lower index,
// drop the nearest = self). One block per batch, one thread per point.
// dist2 computed with explicit rn mul/add (no fma contraction) to match numpy.
// Masked center points skipped entirely (their output rows are zeroed anyway;
// mlp clamps whatever garbage is in their knn slots).
// ---------------------------------------------------------------------------
__global__ __launch_bounds__(PP) void knn_kernel(const float* __restrict__ x,
                                                 int* __restrict__ idx_out) {
    const int b = blockIdx.x;
    const int i = threadIdx.x;
    __shared__ float cx[PP], cy[PP], vmask[PP];
    const float* xb = x + (size_t)b * PP * XCH;
    cx[i] = xb[i * XCH + 0];
    cy[i] = xb[i * XCH + 1];
    vmask[i] = xb[i * XCH + (XCH - 1)];
    __syncthreads();

    if (vmask[i] > 0.0f) {
        const float ci_x = cx[i], ci_y = cy[i];
        float dlist[KK + 1];
        int   ilist[KK + 1];
#pragma unroll
        for (int m = 0; m <= KK; ++m) { dlist[m] = 3.0e38f; ilist[m] = -1; }

        for (int j = 0; j < PP; ++j) {
            float dx = ci_x - cx[j];
            float dy = ci_y - cy[j];
            float d = __fadd_rn(__fmul_rn(dx, dx), __fmul_rn(dy, dy));
            if (!(vmask[j] > 0.0f)) d = BIGD;
            if (d < dlist[KK]) {
                // stable sorted insert (ascending dist; equal keys keep earlier j)
#pragma unroll
                for (int m = KK; m >= 1; --m) {
                    if (d < dlist[m]) {
                        bool fromprev = d < dlist[m - 1];
                        dlist[m] = fromprev ? dlist[m - 1] : d;
                        ilist[m] = fromprev ? ilist[m - 1] : j;
                    }
                }
                if (d < dlist[0]) { dlist[0] = d; ilist[0] = j; }
            }
        }

        int* op = idx_out + ((size_t)(b * PP + i)) * KK;
#pragma unroll
        for (int m = 1; m <= KK; ++m) op[m - 1] = ilist[m];
    }
}

// ---------------------------------------------------------------------------
// Kernel 1b: pack W2 (128x256 fp32) into bf16 B-fragment order for
// mfma_f32_16x16x32_bf16. Fragment for (col-tile ct, k-step ks), lane l,
// element j is B[k = ks*32 + (l>>4)*8 + j][n = ct*16 + (l&15)].
// Layout: W2p[((ct*4 + ks)*64 + l)*8 + j]. 64 KB total, L2-resident.
// ---------------------------------------------------------------------------
__global__ __launch_bounds__(256) void pack_w2_kernel(const float* __restrict__ W2,
                                                      __bf16* __restrict__ W2p) {
    const int t = blockIdx.x * 256 + threadIdx.x;  // 0 .. 32767
    const int j  = t & 7;
    const int l  = (t >> 3) & 63;
    const int ks = (t >> 9) & 3;
    const int ct = t >> 11;
    const int row = ks * 32 + ((l >> 4) * 8) + j;
    const int col = ct * 16 + (l & 15);
    W2p[t] = (__bf16)W2[row * OO + col];
}

// ---------------------------------------------------------------------------
// Kernel 2: fused edge-MLP. One block = GPT(4) points = 64 edge rows.
// edges(64x18,fp32 LDS) -> GEMM1 on VALU -> h1(64x128, bf16 LDS)
// -> GEMM2 on MFMA (bf16, fp32 acc): M=64,N=256,K=128
//    wave w owns cols [64w,64w+64), all 4 row-tiles (1 row-tile = 1 point)
// -> relu + per-tile column sum (= K-mean) -> out (x mask).
// Fully-masked blocks (mask is a prefix per batch) write zeros and exit.
// ---------------------------------------------------------------------------
__global__ __launch_bounds__(256) void mlp_kernel(const float* __restrict__ x,
                                                  const int* __restrict__ knn,
                                                  const float* __restrict__ W1,
                                                  const float* __restrict__ b1,
                                                  const __bf16* __restrict__ W2p,
                                                  const float* __restrict__ b2,
                                                  float* __restrict__ out) {
    __shared__ float  sW1[EE][HH];        // 9216 B
    __shared__ float  sb1[HH];
    __shared__ float  sb2[OO];
    __shared__ float  sedge[64][20];      // 18 channels + pad to float4 row
    __shared__ __bf16 sh1[64][HH + 8];    // +8 bf16 pad: 272B row -> 2-way-free b128 reads
    __shared__ float  sred[GPT][OO][4];   // per-quad column partial sums, 16 KB
    __shared__ float  smask[GPT];

    const int tid = threadIdx.x;
    const int pbase = blockIdx.x * GPT;
    const int bidx = pbase >> 7;          // / PP  (GPT divides PP: block within 1 batch)
    const int i0 = pbase & (PP - 1);
    const float* xb = x + (size_t)bidx * PP * XCH;
    float* outrow = out + (size_t)pbase * (OO + 1);

    if (tid < GPT) smask[tid] = xb[(i0 + tid) * XCH + (XCH - 1)];
    __syncthreads();
    const bool allmasked =
        (smask[0] == 0.0f) & (smask[1] == 0.0f) & (smask[2] == 0.0f) & (smask[3] == 0.0f);
    if (allmasked) {
        // output is re-poisoned before every launch: must write zeros
        for (int o = tid; o < GPT * (OO + 1); o += 256) outrow[o] = 0.0f;
        return;
    }

    // ---- stage W1 / b1 / b2 ----
    for (int t = tid; t < EE * HH; t += 256) sW1[t / HH][t % HH] = W1[t];
    if (tid < HH) sb1[tid] = b1[tid];
    sb2[tid] = b2[tid];  // OO == 256 == blockDim

    // ---- build edge rows: row = tid/4 (0..63), part = tid%4 -> ~5 channels ----
    {
        const int row = tid >> 2;
        const int part = tid & 3;
        const int g = row >> 4;       // point within block
        const int k = row & (KK - 1); // neighbor slot
        const int i = i0 + g;
        int j = knn[(size_t)(pbase + g) * KK + k];
        j = (j < 0) ? 0 : (j > PP - 1 ? PP - 1 : j);  // clamp poison for masked rows
        const int clo = part * 5;
        const int chi = (clo + 5 < EE) ? clo + 5 : EE;
        for (int c = clo; c < chi; ++c) {
            float v;
            if (c < CC + FF) {
                v = xb[i * XCH + c];                      // center coords+feats
            } else {
                int cc = c - (CC + FF);                   // x channel 0..8
                v = xb[j * XCH + cc] - xb[i * XCH + cc];  // neighbor diff
            }
            sedge[row][c] = v;
        }
    }
    __syncthreads();

    // ---- GEMM1 (VALU fp32): h1[64][128] = relu(edge @ W1 + b1), write bf16 ----
    {
        const int colp = (tid & 63) * 2;   // column pair
        const int rgrp = tid >> 6;         // wave id = row group (uniform per wave)
        float w1a[EE], w1b[EE];
#pragma unroll
        for (int c = 0; c < EE; ++c) { w1a[c] = sW1[c][colp]; w1b[c] = sW1[c][colp + 1]; }
        const float ba = sb1[colp], bb = sb1[colp + 1];
        for (int rr = 0; rr < 16; ++rr) {
            const int row = rgrp * 16 + rr;
            const float4* ep = (const float4*)sedge[row];  // whole-wave broadcast reads
            const float4 e0 = ep[0], e1 = ep[1], e2 = ep[2], e3 = ep[3];
            const float2 e4 = *(const float2*)&sedge[row][16];
            const float ev[EE] = {e0.x, e0.y, e0.z, e0.w, e1.x, e1.y, e1.z, e1.w,
                                  e2.x, e2.y, e2.z, e2.w, e3.x, e3.y, e3.z, e3.w,
                                  e4.x, e4.y};
            float aacc = ba, bacc = bb;
#pragma unroll
            for (int c = 0; c < EE; ++c) {
                aacc = fmaf(ev[c], w1a[c], aacc);
                bacc = fmaf(ev[c], w1b[c], bacc);
            }
            bf16x2 hv;
            hv.x = (__bf16)fmaxf(aacc, 0.0f);
            hv.y = (__bf16)fmaxf(bacc, 0.0f);
            *(bf16x2*)&sh1[row][colp] = hv;   // 4B aligned, conflict-free
        }
    }
    __syncthreads();

    // ---- GEMM2 (MFMA bf16): h2[64][256] = relu(h1 @ W2 + b2), fused K-mean ----
    const int lane = tid & 63;
    const int w = tid >> 6;        // wave id: cols [64w, 64w+64)
    const int quad = lane >> 4;
    const int lcol = lane & 15;

    f32x4 acc[GPT][4];
    const f32x4 z4 = {0.0f, 0.0f, 0.0f, 0.0f};
#pragma unroll
    for (int g = 0; g < GPT; ++g)
#pragma unroll
        for (int ct = 0; ct < 4; ++ct) acc[g][ct] = z4;

#pragma unroll
    for (int ks = 0; ks < 4; ++ks) {
        const int kbase = ks * 32 + quad * 8;
        bf16x8 afrag[GPT], bfrag[4];
#pragma unroll
        for (int g = 0; g < GPT; ++g)
            afrag[g] = *(const bf16x8*)&sh1[g * 16 + lcol][kbase];  // ds_read_b128
#pragma unroll
        for (int ct = 0; ct < 4; ++ct) {
            const int ctg = w * 4 + ct;
            bfrag[ct] = *(const bf16x8*)&W2p[(size_t)(((ctg * 4 + ks) * 64 + lane) * 8)];
        }
#pragma unroll
        for (int g = 0; g < GPT; ++g)
#pragma unroll
            for (int ct = 0; ct < 4; ++ct)
                acc[g][ct] = __builtin_amdgcn_mfma_f32_16x16x32_bf16(
                    afrag[g], bfrag[ct], acc[g][ct], 0, 0, 0);
    }

    // ---- epilogue: relu(+b2), per-tile column sum over this quad's 4 rows ----
    // C/D layout: col = lane&15, row = quad*4 + reg  => tile g covers exactly
    // the 16 neighbors of point g, so column-sum of the tile == K-sum.
#pragma unroll
    for (int g = 0; g < GPT; ++g)
#pragma unroll
        for (int ct = 0; ct < 4; ++ct) {
            const int col = w * 64 + ct * 16 + lcol;
            const float bc = sb2[col];
            float s = 0.0f;
#pragma unroll
            for (int r = 0; r < 4; ++r) s += fmaxf(acc[g][ct][r] + bc, 0.0f);
            sred[g][col][quad] = s;
        }
    __syncthreads();

    // ---- combine quad partials, scale by 1/K, mask, append ones channel ----
    for (int o = tid; o < GPT * (OO + 1); o += 256) {
        const int g = o / (OO + 1);
        const int c = o - g * (OO + 1);
        const float m = smask[g];
        float v;
        if (c < OO) {
            const float4 p = *(const float4*)sred[g][c];
            v = (p.x + p.y + p.z + p.w) * (1.0f / KK);
        } else {
            v = 1.0f;
        }
        outrow[o] = v * m;
    }
}

extern "C" void kernel_launch(void* const* d_in, const int* in_sizes, int n_in,
                              void* d_out, int out_size, void* d_ws, size_t ws_size,
                              hipStream_t stream) {
    const float* x  = (const float*)d_in[0];
    const float* W1 = (const float*)d_in[1];
    const float* b1 = (const float*)d_in[2];
    const float* W2 = (const float*)d_in[3];
    const float* b2 = (const float*)d_in[4];
    float* out = (float*)d_out;

    int* knn_idx = (int*)d_ws;                                   // 2 MB
    __bf16* W2p = (__bf16*)((char*)d_ws + 2 * 1024 * 1024);      // 64 KB

    knn_kernel<<<BB, PP, 0, stream>>>(x, knn_idx);
    pack_w2_kernel<<<128, 256, 0, stream>>>(W2, W2p);

    const int nblocks = (BB * PP) / GPT;  // 8192
    mlp_kernel<<<nblocks, 256, 0, stream>>>(x, knn_idx, W1, b1, W2p, b2, out);
}

// Round 3
// 190.488 us; speedup vs baseline: 3.0298x; 1.1237x over previous
//
#include <hip/hip_runtime.h>

// Problem constants
#define BB 256
#define PP 128
#define CC 2
#define FF 7
#define KK 16
#define HH 128
#define OO 256
#define EE 18      // 2*(C+F)
#define XCH 10     // C + F + 1 (coords, feats, mask)
#define BIGD 1000000000.0f
#define GPT 4      // points per block in MLP kernel

typedef __bf16 bf16x8 __attribute__((ext_vector_type(8)));
typedef __bf16 bf16x4 __attribute__((ext_vector_type(4)));
typedef float  f32x4  __attribute__((ext_vector_type(4)));

// ---------------------------------------------------------------------------
// Kernel 1: exact KNN, one WAVE per point (32768 waves -> full occupancy,
// vs round-1's 512 long latency-bound waves). Lane l holds candidates j=l and
// j=l+64. 17 rounds of lexicographic (d, j) butterfly-min reproduce
// jax.lax.top_k's stable ascending order exactly; round 0 discards the
// global min (self). dist2 uses __fmul_rn/__fadd_rn to match numpy bit-exact
// (required: a swapped boundary neighbor changes the output by >> threshold).
// Masked center points: skip entirely (mlp clamps their poisoned knn slots).
// ---------------------------------------------------------------------------
__global__ __launch_bounds__(256) void knn_kernel(const float* __restrict__ x,
                                                  int* __restrict__ idx_out) {
    const int tid = threadIdx.x;
    const int lane = tid & 63;
    const int p = blockIdx.x * 4 + (tid >> 6);
    const int b = p >> 7;
    const int i = p & (PP - 1);
    const float* xb = x + (size_t)b * PP * XCH;

    if (xb[i * XCH + (XCH - 1)] <= 0.0f) return;  // wave-uniform exit

    const float cix = xb[i * XCH + 0];
    const float ciy = xb[i * XCH + 1];

    const int j0 = lane, j1 = lane + 64;
    float d0, d1;
    {
        float m0 = xb[j0 * XCH + (XCH - 1)];
        float dx = cix - xb[j0 * XCH + 0];
        float dy = ciy - xb[j0 * XCH + 1];
        d0 = __fadd_rn(__fmul_rn(dx, dx), __fmul_rn(dy, dy));
        if (m0 <= 0.0f) d0 = BIGD;
    }
    {
        float m1 = xb[j1 * XCH + (XCH - 1)];
        float dx = cix - xb[j1 * XCH + 0];
        float dy = ciy - xb[j1 * XCH + 1];
        d1 = __fadd_rn(__fmul_rn(dx, dx), __fmul_rn(dy, dy));
        if (m1 <= 0.0f) d1 = BIGD;
    }

    int keep = 0;
#pragma unroll
    for (int r = 0; r < KK + 1; ++r) {
        float dm; int jm;
        if (d1 < d0) { dm = d1; jm = j1; } else { dm = d0; jm = j0; }
#pragma unroll
        for (int s = 1; s < 64; s <<= 1) {
            float dd = __shfl_xor(dm, s, 64);
            int   jj = __shfl_xor(jm, s, 64);
            if (dd < dm || (dd == dm && jj < jm)) { dm = dd; jm = jj; }
        }
        if (r > 0 && lane == r - 1) keep = jm;
        if (jm == j0) d0 = 3.0e38f;   // consume winner (j unique -> one lane)
        if (jm == j1) d1 = 3.0e38f;
    }
    if (lane < KK) idx_out[(size_t)p * KK + lane] = keep;
}

// ---------------------------------------------------------------------------
// Kernel 1b: pack W2 and W1 into bf16 MFMA fragment order.
// W2p (B-frag, 16x16x32): [ct 16][ks 4][lane 64][j 8], elem = W2[ks*32+(l>>4)*8+j][ct*16+(l&15)]
// W1p (A-frag for h1^T = W1^T @ edge^T): [nt 8][lane 64][j 8],
//   elem = W1[k][nt*16+(l&15)] for k=(l>>4)*8+j < 18, else 0 (K padded to 32).
// ---------------------------------------------------------------------------
__global__ __launch_bounds__(256) void pack_w_kernel(const float* __restrict__ W1,
                                                     const float* __restrict__ W2,
                                                     __bf16* __restrict__ W2p,
                                                     __bf16* __restrict__ W1p) {
    const int t = blockIdx.x * 256 + threadIdx.x;  // 0 .. 36863
    if (t < 32768) {
        const int j  = t & 7;
        const int l  = (t >> 3) & 63;
        const int ks = (t >> 9) & 3;
        const int ct = t >> 11;
        const int row = ks * 32 + ((l >> 4) * 8) + j;
        const int col = ct * 16 + (l & 15);
        W2p[t] = (__bf16)W2[row * OO + col];
    } else {
        const int t2 = t - 32768;  // 0 .. 4095
        const int j  = t2 & 7;
        const int l  = (t2 >> 3) & 63;
        const int nt = t2 >> 9;
        const int k  = ((l >> 4) * 8) + j;
        const int n  = nt * 16 + (l & 15);
        W1p[t2] = (k < EE) ? (__bf16)W1[k * HH + n] : (__bf16)0.0f;
    }
}

// ---------------------------------------------------------------------------
// Kernel 2: fused edge-MLP, all-MFMA. One block = 4 points = 64 edge rows,
// 4 waves; wave w owns edge-row tile w (GEMM1) and output cols [64w,64w+64)
// (GEMM2).
//  - Edge build: thread (w*64+l) computes exactly the GEMM1 B-fragment lane l
//    of tile w needs (row = l&15 = neighbor slot, k = (l>>4)*8.. = channels)
//    -> edges live only in registers, no LDS, no barrier.
//  - GEMM1 (MFMA): h1^T tiles = W1p-frag x edge-frag; relu+bias; bf16 b64
//    writes into sh1A in GEMM2 A-frag order (2-way banks = free).
//  - GEMM2 (MFMA): 64 MFMA/wave; epilogue relu+bias, tile-column sum = K-sum
//    via shfl_xor(16/32); direct coalesced stores. 2 barriers total.
// ---------------------------------------------------------------------------
__global__ __launch_bounds__(256, 4) void mlp_kernel(const float* __restrict__ x,
                                                     const int* __restrict__ knn,
                                                     const __bf16* __restrict__ W1p,
                                                     const float* __restrict__ b1,
                                                     const __bf16* __restrict__ W2p,
                                                     const float* __restrict__ b2,
                                                     float* __restrict__ out) {
    __shared__ __bf16 sh1A[16 * 64 * 8];  // [ks*4+g][lane][j], 16 KB
    __shared__ float  sb1[HH];
    __shared__ float  sb2[OO];
    __shared__ float  smask[GPT];

    const int tid = threadIdx.x;
    const int lane = tid & 63;
    const int w = tid >> 6;
    const int quad = lane >> 4;
    const int lcol = lane & 15;

    const int pbase = blockIdx.x * GPT;
    const int bidx = pbase >> 7;
    const int i0 = pbase & (PP - 1);
    const float* xb = x + (size_t)bidx * PP * XCH;
    float* outrow = out + (size_t)pbase * (OO + 1);

    if (tid < HH) sb1[tid] = b1[tid];
    sb2[tid] = b2[tid];
    if (tid < GPT) smask[tid] = xb[(i0 + tid) * XCH + (XCH - 1)];
    __syncthreads();

    const bool allmasked =
        (smask[0] == 0.0f) & (smask[1] == 0.0f) & (smask[2] == 0.0f) & (smask[3] == 0.0f);
    if (allmasked) {
        // out is re-poisoned before every launch: must write zeros
        for (int o = tid; o < GPT * (OO + 1); o += 256) outrow[o] = 0.0f;
        return;  // uniform: all threads exit, no barrier mismatch
    }

    // ---- edge build, straight into the GEMM1 B-fragment (registers only) ----
    // this thread: point g=w, neighbor slot lcol, channel block quad (8 ch)
    const int i = i0 + w;
    int jn = knn[(size_t)(pbase + w) * KK + lcol];
    jn = (jn < 0) ? 0 : (jn > PP - 1 ? PP - 1 : jn);  // clamp ws-poison (masked rows)
    const float* ci = xb + i * XCH;
    const float* cj = xb + jn * XCH;
    // rows are 40 B apart -> 8 B aligned: use float2 loads
    const float2 a01 = *(const float2*)(ci + 0);
    const float2 a23 = *(const float2*)(ci + 2);
    const float2 a45 = *(const float2*)(ci + 4);
    const float2 a67 = *(const float2*)(ci + 6);
    const float  a8  = ci[8];
    const float2 n01 = *(const float2*)(cj + 0);
    const float2 n23 = *(const float2*)(cj + 2);
    const float2 n45 = *(const float2*)(cj + 4);
    const float2 n67 = *(const float2*)(cj + 6);
    const float  n8  = cj[8];

    float v[8];
#pragma unroll
    for (int e = 0; e < 8; ++e) v[e] = 0.0f;
    if (quad == 0) {           // channels 0..7 = center ch 0..7
        v[0] = a01.x; v[1] = a01.y; v[2] = a23.x; v[3] = a23.y;
        v[4] = a45.x; v[5] = a45.y; v[6] = a67.x; v[7] = a67.y;
    } else if (quad == 1) {    // ch 8 = center ch8; ch 9..15 = diff ch 0..6
        v[0] = a8;
        v[1] = n01.x - a01.x; v[2] = n01.y - a01.y;
        v[3] = n23.x - a23.x; v[4] = n23.y - a23.y;
        v[5] = n45.x - a45.x; v[6] = n45.y - a45.y;
        v[7] = n67.x - a67.x;
    } else if (quad == 2) {    // ch 16 = diff ch7; ch 17 = diff ch8; rest 0
        v[0] = n67.y - a67.y;
        v[1] = n8 - a8;
    }                          // quad 3: zero padding (K 18 -> 32)

    bf16x8 ef;
#pragma unroll
    for (int e = 0; e < 8; ++e) ef[e] = (__bf16)v[e];

    // ---- GEMM1 (MFMA): h1^T tiles; A = W1p frags (global/L2), B = ef ----
    bf16x8 wf[8];
#pragma unroll
    for (int nt = 0; nt < 8; ++nt)
        wf[nt] = *(const bf16x8*)&W1p[(size_t)((nt * 64 + lane) * 8)];

    const f32x4 z4 = {0.0f, 0.0f, 0.0f, 0.0f};
    f32x4 h[8];
#pragma unroll
    for (int nt = 0; nt < 8; ++nt)
        h[nt] = __builtin_amdgcn_mfma_f32_16x16x32_bf16(wf[nt], ef, z4, 0, 0, 0);

    // ---- epilogue 1: relu(+b1), write bf16 into GEMM2 A-frag order ----
    // C layout: col = lcol = edge row (within tile w), row = quad*4+r = h1
    // feature m = GEMM2's k. 4 consecutive k per (nt,quad) -> one b64 write.
#pragma unroll
    for (int nt = 0; nt < 8; ++nt) {
        const int ks = nt >> 1;
        const int lp = (((nt * 2 + (quad >> 1)) & 3) << 4) | lcol;
        bf16x4 hv;
#pragma unroll
        for (int r = 0; r < 4; ++r) {
            const int m = nt * 16 + quad * 4 + r;
            hv[r] = (__bf16)fmaxf(h[nt][r] + sb1[m], 0.0f);
        }
        *(bf16x4*)&sh1A[((ks * 4 + w) * 64 + lp) * 8 + (quad & 1) * 4] = hv;
    }
    __syncthreads();

    // ---- GEMM2 (MFMA): h2[64][256] = relu(h1 @ W2 + b2), fused K-mean ----
    f32x4 acc[GPT][4];
#pragma unroll
    for (int g = 0; g < GPT; ++g)
#pragma unroll
        for (int ct = 0; ct < 4; ++ct) acc[g][ct] = z4;

#pragma unroll
    for (int ks = 0; ks < 4; ++ks) {
        bf16x8 af[GPT], bfr[4];
#pragma unroll
        for (int g = 0; g < GPT; ++g)
            af[g] = *(const bf16x8*)&sh1A[((ks * 4 + g) * 64 + lane) * 8];
#pragma unroll
        for (int ct = 0; ct < 4; ++ct)
            bfr[ct] = *(const bf16x8*)&W2p[(size_t)((((w * 4 + ct) * 4 + ks) * 64 + lane) * 8)];
#pragma unroll
        for (int g = 0; g < GPT; ++g)
#pragma unroll
            for (int ct = 0; ct < 4; ++ct)
                acc[g][ct] = __builtin_amdgcn_mfma_f32_16x16x32_bf16(
                    af[g], bfr[ct], acc[g][ct], 0, 0, 0);
    }

    // ---- epilogue 2: relu(+b2), K-sum = tile column sum via shuffles ----
    // C layout: col=lcol, row=quad*4+r; tile g's 16 rows = point g's K
    // neighbors. Partial over 4 rows in-lane, then fold quads (xor 16, 32).
    float val[4];
#pragma unroll
    for (int g = 0; g < GPT; ++g) {
#pragma unroll
        for (int ct = 0; ct < 4; ++ct) {
            const int col = w * 64 + ct * 16 + lcol;
            const float bc = sb2[col];
            float s = 0.0f;
#pragma unroll
            for (int r = 0; r < 4; ++r) s += fmaxf(acc[g][ct][r] + bc, 0.0f);
            s += __shfl_xor(s, 16, 64);
            s += __shfl_xor(s, 32, 64);
            if (quad == g) val[ct] = s;   // lane (quad=g, lcol) keeps point g
        }
    }
    const float m = smask[quad] * (1.0f / KK);
#pragma unroll
    for (int ct = 0; ct < 4; ++ct)
        outrow[(size_t)quad * (OO + 1) + w * 64 + ct * 16 + lcol] = val[ct] * m;
    if (tid < GPT) outrow[(size_t)tid * (OO + 1) + OO] = smask[tid];  // ones ch * mask

    (void)knn; (void)x;
}

extern "C" void kernel_launch(void* const* d_in, const int* in_sizes, int n_in,
                              void* d_out, int out_size, void* d_ws, size_t ws_size,
                              hipStream_t stream) {
    const float* x  = (const float*)d_in[0];
    const float* W1 = (const float*)d_in[1];
    const float* b1 = (const float*)d_in[2];
    const float* W2 = (const float*)d_in[3];
    const float* b2 = (const float*)d_in[4];
    float* out = (float*)d_out;

    int* knn_idx = (int*)d_ws;                                        // 2 MB
    __bf16* W2p = (__bf16*)((char*)d_ws + 2 * 1024 * 1024);           // 64 KB
    __bf16* W1p = (__bf16*)((char*)d_ws + 2 * 1024 * 1024 + 65536);   // 8 KB

    knn_kernel<<<(BB * PP) / 4, 256, 0, stream>>>(x, knn_idx);
    pack_w_kernel<<<144, 256, 0, stream>>>(W1, W2, W2p, W1p);

    const int nblocks = (BB * PP) / GPT;  // 8192
    mlp_kernel<<<nblocks, 256, 0, stream>>>(x, knn_idx, W1p, b1, W2p, b2, out);
}

// Round 4
// 138.395 us; speedup vs baseline: 4.1702x; 1.3764x over previous
//
#include <hip/hip_runtime.h>

// Problem constants
#define BB 256
#define PP 128
#define CC 2
#define FF 7
#define KK 16
#define HH 128
#define OO 256
#define EE 18      // 2*(C+F)
#define XCH 10     // C + F + 1 (coords, feats, mask)
#define BIGD 1000000000.0f
#define GPT 4      // points per block in MLP kernel

typedef __bf16 bf16x8 __attribute__((ext_vector_type(8)));
typedef __bf16 bf16x4 __attribute__((ext_vector_type(4)));
typedef float  f32x4  __attribute__((ext_vector_type(4)));

// ---------------------------------------------------------------------------
// Kernel 1: exact KNN via wave-wide bit-serial radix select. One wave per
// point; lane l owns candidates j=l and j=l+64.
// key = (d_bits << 7) | j : 39 bits, unique, and ascending key order ==
// lexicographic (d, j) == jax.lax.top_k's stable order (d>=0 so fp32 bits
// are monotone as uint). Self is the unique d=0 minimum == the "nearest"
// that the reference drops, so exclude it and select the top-16 SET.
// Slot order is arbitrary (mean over K is order-invariant).
// dist2 uses __fmul_rn/__fadd_rn to match numpy bit-exact (a swapped
// boundary neighbor would change the output far beyond tolerance).
// Masked center points skipped (mlp clamps their poisoned knn slots).
// ---------------------------------------------------------------------------
__global__ __launch_bounds__(256) void knn_kernel(const float* __restrict__ x,
                                                  int* __restrict__ idx_out) {
    const int tid = threadIdx.x;
    const int lane = tid & 63;
    const int p = blockIdx.x * 4 + (tid >> 6);
    const int b = p >> 7;
    const int i = p & (PP - 1);
    const float* xb = x + (size_t)b * PP * XCH;

    if (xb[i * XCH + (XCH - 1)] <= 0.0f) return;  // wave-uniform exit

    const float cix = xb[i * XCH + 0];
    const float ciy = xb[i * XCH + 1];

    const int j0 = lane, j1 = lane + 64;
    float d0, d1;
    {
        const float2 c0 = *(const float2*)(xb + j0 * XCH);
        float m0 = xb[j0 * XCH + (XCH - 1)];
        float dx = cix - c0.x, dy = ciy - c0.y;
        d0 = __fadd_rn(__fmul_rn(dx, dx), __fmul_rn(dy, dy));
        if (m0 <= 0.0f || j0 == i) d0 = BIGD;
    }
    {
        const float2 c1 = *(const float2*)(xb + j1 * XCH);
        float m1 = xb[j1 * XCH + (XCH - 1)];
        float dx = cix - c1.x, dy = ciy - c1.y;
        d1 = __fadd_rn(__fmul_rn(dx, dx), __fmul_rn(dy, dy));
        if (m1 <= 0.0f || j1 == i) d1 = BIGD;
    }

    const unsigned long long key0 =
        ((unsigned long long)__float_as_uint(d0) << 7) | (unsigned)j0;
    const unsigned long long key1 =
        ((unsigned long long)__float_as_uint(d1) << 7) | (unsigned)j1;

    // Radix select the 16 smallest keys among the 128 candidates.
    // A*: still-undecided candidates; W*: confirmed winners; need: winners
    // still to pick from A. Invariant: top-`need` of A are all winners.
    unsigned long long A0 = ~0ull, A1 = ~0ull, W0 = 0ull, W1 = 0ull;
    int need = KK;
#pragma unroll 1
    for (int bp = 37; bp >= 0; --bp) {   // bit 38 = fp32 sign = always 0
        const unsigned long long z0 = A0 & __ballot(((key0 >> bp) & 1ull) == 0ull);
        const unsigned long long z1 = A1 & __ballot(((key1 >> bp) & 1ull) == 0ull);
        const int c = __popcll(z0) + __popcll(z1);
        if (c == need) { W0 |= z0; W1 |= z1; need = 0; A0 = A1 = 0ull; break; }
        if (c > need) {            // winners all have bit==0
            A0 = z0; A1 = z1;
        } else {                   // all bit==0 actives win; continue in bit==1
            W0 |= z0; W1 |= z1; need -= c;
            A0 &= ~z0; A1 &= ~z1;
        }
    }
    W0 |= A0; W1 |= A1;  // keys unique => remaining actives are exactly the rest

    // Compact winners to output slots (arbitrary order: lane order).
    unsigned int mb0 = __builtin_amdgcn_mbcnt_lo((unsigned)(W0 & 0xffffffffull), 0u);
    mb0 = __builtin_amdgcn_mbcnt_hi((unsigned)(W0 >> 32), mb0);
    unsigned int mb1 = __builtin_amdgcn_mbcnt_lo((unsigned)(W1 & 0xffffffffull), 0u);
    mb1 = __builtin_amdgcn_mbcnt_hi((unsigned)(W1 >> 32), mb1);
    const int base1 = __popcll(W0);

    int* op = idx_out + (size_t)p * KK;
    if ((W0 >> lane) & 1ull) op[mb0] = j0;
    if ((W1 >> lane) & 1ull) op[base1 + mb1] = j1;
}

// ---------------------------------------------------------------------------
// Kernel 1b: pack W2 and W1 into bf16 MFMA fragment order.
// W2p (B-frag, 16x16x32): [ct 16][ks 4][lane 64][j 8], elem = W2[ks*32+(l>>4)*8+j][ct*16+(l&15)]
// W1p (A-frag for h1^T = W1^T @ edge^T): [nt 8][lane 64][j 8],
//   elem = W1[k][nt*16+(l&15)] for k=(l>>4)*8+j < 18, else 0 (K padded to 32).
// ---------------------------------------------------------------------------
__global__ __launch_bounds__(256) void pack_w_kernel(const float* __restrict__ W1,
                                                     const float* __restrict__ W2,
                                                     __bf16* __restrict__ W2p,
                                                     __bf16* __restrict__ W1p) {
    const int t = blockIdx.x * 256 + threadIdx.x;  // 0 .. 36863
    if (t < 32768) {
        const int j  = t & 7;
        const int l  = (t >> 3) & 63;
        const int ks = (t >> 9) & 3;
        const int ct = t >> 11;
        const int row = ks * 32 + ((l >> 4) * 8) + j;
        const int col = ct * 16 + (l & 15);
        W2p[t] = (__bf16)W2[row * OO + col];
    } else {
        const int t2 = t - 32768;  // 0 .. 4095
        const int j  = t2 & 7;
        const int l  = (t2 >> 3) & 63;
        const int nt = t2 >> 9;
        const int k  = ((l >> 4) * 8) + j;
        const int n  = nt * 16 + (l & 15);
        W1p[t2] = (k < EE) ? (__bf16)W1[k * HH + n] : (__bf16)0.0f;
    }
}

// ---------------------------------------------------------------------------
// Kernel 2: fused edge-MLP, all-MFMA. One block = 4 points = 64 edge rows,
// 4 waves; wave w owns edge-row tile w (GEMM1) and output cols [64w,64w+64)
// (GEMM2).
//  - Edge build: thread (w*64+l) computes exactly the GEMM1 B-fragment lane l
//    of tile w needs (row = l&15 = neighbor slot, k = (l>>4)*8.. = channels)
//    -> edges live only in registers, no LDS, no barrier.
//  - GEMM1 (MFMA): h1^T tiles = W1p-frag x edge-frag; relu+bias; bf16 b64
//    writes into sh1A in GEMM2 A-frag order (2-way banks = free).
//  - GEMM2 (MFMA): 64 MFMA/wave; epilogue relu+bias, tile-column sum = K-sum
//    via shfl_xor(16/32); direct coalesced stores. 2 barriers total.
// ---------------------------------------------------------------------------
__global__ __launch_bounds__(256, 4) void mlp_kernel(const float* __restrict__ x,
                                                     const int* __restrict__ knn,
                                                     const __bf16* __restrict__ W1p,
                                                     const float* __restrict__ b1,
                                                     const __bf16* __restrict__ W2p,
                                                     const float* __restrict__ b2,
                                                     float* __restrict__ out) {
    __shared__ __bf16 sh1A[16 * 64 * 8];  // [ks*4+g][lane][j], 16 KB
    __shared__ float  sb1[HH];
    __shared__ float  sb2[OO];
    __shared__ float  smask[GPT];

    const int tid = threadIdx.x;
    const int lane = tid & 63;
    const int w = tid >> 6;
    const int quad = lane >> 4;
    const int lcol = lane & 15;

    const int pbase = blockIdx.x * GPT;
    const int bidx = pbase >> 7;
    const int i0 = pbase & (PP - 1);
    const float* xb = x + (size_t)bidx * PP * XCH;
    float* outrow = out + (size_t)pbase * (OO + 1);

    if (tid < HH) sb1[tid] = b1[tid];
    sb2[tid] = b2[tid];
    if (tid < GPT) smask[tid] = xb[(i0 + tid) * XCH + (XCH - 1)];
    __syncthreads();

    const bool allmasked =
        (smask[0] == 0.0f) & (smask[1] == 0.0f) & (smask[2] == 0.0f) & (smask[3] == 0.0f);
    if (allmasked) {
        // out is re-poisoned before every launch: must write zeros
        for (int o = tid; o < GPT * (OO + 1); o += 256) outrow[o] = 0.0f;
        return;  // uniform: all threads exit, no barrier mismatch
    }

    // ---- edge build, straight into the GEMM1 B-fragment (registers only) ----
    // this thread: point g=w, neighbor slot lcol, channel block quad (8 ch)
    const int i = i0 + w;
    int jn = knn[(size_t)(pbase + w) * KK + lcol];
    jn = (jn < 0) ? 0 : (jn > PP - 1 ? PP - 1 : jn);  // clamp ws-poison (masked rows)
    const float* ci = xb + i * XCH;
    const float* cj = xb + jn * XCH;
    // rows are 40 B apart -> 8 B aligned: use float2 loads
    const float2 a01 = *(const float2*)(ci + 0);
    const float2 a23 = *(const float2*)(ci + 2);
    const float2 a45 = *(const float2*)(ci + 4);
    const float2 a67 = *(const float2*)(ci + 6);
    const float  a8  = ci[8];
    const float2 n01 = *(const float2*)(cj + 0);
    const float2 n23 = *(const float2*)(cj + 2);
    const float2 n45 = *(const float2*)(cj + 4);
    const float2 n67 = *(const float2*)(cj + 6);
    const float  n8  = cj[8];

    float v[8];
#pragma unroll
    for (int e = 0; e < 8; ++e) v[e] = 0.0f;
    if (quad == 0) {           // channels 0..7 = center ch 0..7
        v[0] = a01.x; v[1] = a01.y; v[2] = a23.x; v[3] = a23.y;
        v[4] = a45.x; v[5] = a45.y; v[6] = a67.x; v[7] = a67.y;
    } else if (quad == 1) {    // ch 8 = center ch8; ch 9..15 = diff ch 0..6
        v[0] = a8;
        v[1] = n01.x - a01.x; v[2] = n01.y - a01.y;
        v[3] = n23.x - a23.x; v[4] = n23.y - a23.y;
        v[5] = n45.x - a45.x; v[6] = n45.y - a45.y;
        v[7] = n67.x - a67.x;
    } else if (quad == 2) {    // ch 16 = diff ch7; ch 17 = diff ch8; rest 0
        v[0] = n67.y - a67.y;
        v[1] = n8 - a8;
    }                          // quad 3: zero padding (K 18 -> 32)

    bf16x8 ef;
#pragma unroll
    for (int e = 0; e < 8; ++e) ef[e] = (__bf16)v[e];

    // ---- GEMM1 (MFMA): h1^T tiles; A = W1p frags (global/L2), B = ef ----
    bf16x8 wf[8];
#pragma unroll
    for (int nt = 0; nt < 8; ++nt)
        wf[nt] = *(const bf16x8*)&W1p[(size_t)((nt * 64 + lane) * 8)];

    const f32x4 z4 = {0.0f, 0.0f, 0.0f, 0.0f};
    f32x4 h[8];
#pragma unroll
    for (int nt = 0; nt < 8; ++nt)
        h[nt] = __builtin_amdgcn_mfma_f32_16x16x32_bf16(wf[nt], ef, z4, 0, 0, 0);

    // ---- epilogue 1: relu(+b1), write bf16 into GEMM2 A-frag order ----
    // C layout: col = lcol = edge row (within tile w), row = quad*4+r = h1
    // feature m = GEMM2's k. 4 consecutive k per (nt,quad) -> one b64 write.
#pragma unroll
    for (int nt = 0; nt < 8; ++nt) {
        const int ks = nt >> 1;
        const int lp = (((nt * 2 + (quad >> 1)) & 3) << 4) | lcol;
        bf16x4 hv;
#pragma unroll
        for (int r = 0; r < 4; ++r) {
            const int m = nt * 16 + quad * 4 + r;
            hv[r] = (__bf16)fmaxf(h[nt][r] + sb1[m], 0.0f);
        }
        *(bf16x4*)&sh1A[((ks * 4 + w) * 64 + lp) * 8 + (quad & 1) * 4] = hv;
    }
    __syncthreads();

    // ---- GEMM2 (MFMA): h2[64][256] = relu(h1 @ W2 + b2), fused K-mean ----
    f32x4 acc[GPT][4];
#pragma unroll
    for (int g = 0; g < GPT; ++g)
#pragma unroll
        for (int ct = 0; ct < 4; ++ct) acc[g][ct] = z4;

#pragma unroll
    for (int ks = 0; ks < 4; ++ks) {
        bf16x8 af[GPT], bfr[4];
#pragma unroll
        for (int g = 0; g < GPT; ++g)
            af[g] = *(const bf16x8*)&sh1A[((ks * 4 + g) * 64 + lane) * 8];
#pragma unroll
        for (int ct = 0; ct < 4; ++ct)
            bfr[ct] = *(const bf16x8*)&W2p[(size_t)((((w * 4 + ct) * 4 + ks) * 64 + lane) * 8)];
#pragma unroll
        for (int g = 0; g < GPT; ++g)
#pragma unroll
            for (int ct = 0; ct < 4; ++ct)
                acc[g][ct] = __builtin_amdgcn_mfma_f32_16x16x32_bf16(
                    af[g], bfr[ct], acc[g][ct], 0, 0, 0);
    }

    // ---- epilogue 2: relu(+b2), K-sum = tile column sum via shuffles ----
    // C layout: col=lcol, row=quad*4+r; tile g's 16 rows = point g's K
    // neighbors. Partial over 4 rows in-lane, then fold quads (xor 16, 32).
    float val[4];
#pragma unroll
    for (int g = 0; g < GPT; ++g) {
#pragma unroll
        for (int ct = 0; ct < 4; ++ct) {
            const int col = w * 64 + ct * 16 + lcol;
            const float bc = sb2[col];
            float s = 0.0f;
#pragma unroll
            for (int r = 0; r < 4; ++r) s += fmaxf(acc[g][ct][r] + bc, 0.0f);
            s += __shfl_xor(s, 16, 64);
            s += __shfl_xor(s, 32, 64);
            if (quad == g) val[ct] = s;   // lane (quad=g, lcol) keeps point g
        }
    }
    const float m = smask[quad] * (1.0f / KK);
#pragma unroll
    for (int ct = 0; ct < 4; ++ct)
        outrow[(size_t)quad * (OO + 1) + w * 64 + ct * 16 + lcol] = val[ct] * m;
    if (tid < GPT) outrow[(size_t)tid * (OO + 1) + OO] = smask[tid];  // ones ch * mask

    (void)knn; (void)x;
}

extern "C" void kernel_launch(void* const* d_in, const int* in_sizes, int n_in,
                              void* d_out, int out_size, void* d_ws, size_t ws_size,
                              hipStream_t stream) {
    const float* x  = (const float*)d_in[0];
    const float* W1 = (const float*)d_in[1];
    const float* b1 = (const float*)d_in[2];
    const float* W2 = (const float*)d_in[3];
    const float* b2 = (const float*)d_in[4];
    float* out = (float*)d_out;

    int* knn_idx = (int*)d_ws;                                        // 2 MB
    __bf16* W2p = (__bf16*)((char*)d_ws + 2 * 1024 * 1024);           // 64 KB
    __bf16* W1p = (__bf16*)((char*)d_ws + 2 * 1024 * 1024 + 65536);   // 8 KB

    knn_kernel<<<(BB * PP) / 4, 256, 0, stream>>>(x, knn_idx);
    pack_w_kernel<<<144, 256, 0, stream>>>(W1, W2, W2p, W1p);

    const int nblocks = (BB * PP) / GPT;  // 8192
    mlp_kernel<<<nblocks, 256, 0, stream>>>(x, knn_idx, W1p, b1, W2p, b2, out);
}

// Round 5
// 129.452 us; speedup vs baseline: 4.4582x; 1.0691x over previous
//
#include <hip/hip_runtime.h>

// Problem constants
#define BB 256
#define PP 128
#define CC 2
#define FF 7
#define KK 16
#define HH 128
#define OO 256
#define EE 18      // 2*(C+F)
#define XCH 10     // C + F + 1 (coords, feats, mask)
#define BIGD 1000000000.0f
#define GPT 4      // points per block in MLP kernel

typedef __bf16 bf16x8 __attribute__((ext_vector_type(8)));
typedef __bf16 bf16x4 __attribute__((ext_vector_type(4)));
typedef float  f32x4  __attribute__((ext_vector_type(4)));

// ---------------------------------------------------------------------------
// Kernel 1: pack W2 and W1 into bf16 MFMA fragment order.
// W2p (B-frag, 16x16x32): [ct 16][ks 4][lane 64][j 8], elem = W2[ks*32+(l>>4)*8+j][ct*16+(l&15)]
// W1p (A-frag for h1^T = W1^T @ edge^T): [nt 8][lane 64][j 8],
//   elem = W1[k][nt*16+(l&15)] for k=(l>>4)*8+j < 18, else 0 (K padded to 32).
// ---------------------------------------------------------------------------
__global__ __launch_bounds__(256) void pack_w_kernel(const float* __restrict__ W1,
                                                     const float* __restrict__ W2,
                                                     __bf16* __restrict__ W2p,
                                                     __bf16* __restrict__ W1p) {
    const int t = blockIdx.x * 256 + threadIdx.x;  // 0 .. 36863
    if (t < 32768) {
        const int j  = t & 7;
        const int l  = (t >> 3) & 63;
        const int ks = (t >> 9) & 3;
        const int ct = t >> 11;
        const int row = ks * 32 + ((l >> 4) * 8) + j;
        const int col = ct * 16 + (l & 15);
        W2p[t] = (__bf16)W2[row * OO + col];
    } else {
        const int t2 = t - 32768;  // 0 .. 4095
        const int j  = t2 & 7;
        const int l  = (t2 >> 3) & 63;
        const int nt = t2 >> 9;
        const int k  = ((l >> 4) * 8) + j;
        const int n  = nt * 16 + (l & 15);
        W1p[t2] = (k < EE) ? (__bf16)W1[k * HH + n] : (__bf16)0.0f;
    }
}

// ---------------------------------------------------------------------------
// Kernel 2: fully-fused EdgeConv: per-block KNN + edge-MLP (all-MFMA).
// One block = 4 points = 64 edge rows, 4 waves.
//
//  - KNN (wave w, point w): radix select over 128 candidates (lane l owns
//    j=l and j=l+64). key = (d_bits << 7) | j : unique, ascending key order
//    == lexicographic (d, j) == jax.lax.top_k's stable order (d >= 0 so fp32
//    bits are monotone as uint). Self is the unique d=0 min == the dropped
//    "nearest", so exclude it and select the top-16 SET (slot order is
//    irrelevant: mean over K is order-invariant). Distance bits (31) use
//    32-bit ops with wave ballots; the low 7 index bits use compile-time
//    constant ballot masks. dist2 = __fmul_rn/__fadd_rn to match numpy
//    bit-exact. Winners land in sknn[w][0..15] (per-wave LDS).
//  - Edge build: thread (w*64+l) computes exactly the GEMM1 B-fragment lane
//    l of tile w needs -> edges live only in registers.
//  - GEMM1 (MFMA): h1^T tiles = W1p-frag x edge-frag; relu+bias; bf16 b64
//    writes into sh1A in GEMM2 A-frag order (2-way banks = free).
//  - GEMM2 (MFMA): 64 MFMA/wave; epilogue relu+bias, tile-column sum = K-sum
//    via shfl_xor(16/32); direct coalesced stores. 3 barriers total.
// ---------------------------------------------------------------------------
__global__ __launch_bounds__(256, 4) void mlp_kernel(const float* __restrict__ x,
                                                     const __bf16* __restrict__ W1p,
                                                     const float* __restrict__ b1,
                                                     const __bf16* __restrict__ W2p,
                                                     const float* __restrict__ b2,
                                                     float* __restrict__ out) {
    __shared__ __bf16 sh1A[16 * 64 * 8];  // [ks*4+g][lane][j], 16 KB
    __shared__ float  sb1[HH];
    __shared__ float  sb2[OO];
    __shared__ float  smask[GPT];
    __shared__ int    sknn[GPT][KK];      // per-wave winner slots

    const int tid = threadIdx.x;
    const int lane = tid & 63;
    const int w = tid >> 6;
    const int quad = lane >> 4;
    const int lcol = lane & 15;

    const int pbase = blockIdx.x * GPT;
    const int bidx = pbase >> 7;
    const int i0 = pbase & (PP - 1);
    const float* xb = x + (size_t)bidx * PP * XCH;
    float* outrow = out + (size_t)pbase * (OO + 1);

    if (tid < HH) sb1[tid] = b1[tid];
    sb2[tid] = b2[tid];
    if (tid < GPT) smask[tid] = xb[(i0 + tid) * XCH + (XCH - 1)];
    __syncthreads();

    const bool allmasked =
        (smask[0] == 0.0f) & (smask[1] == 0.0f) & (smask[2] == 0.0f) & (smask[3] == 0.0f);
    if (allmasked) {
        // out is re-poisoned before every launch: must write zeros
        for (int o = tid; o < GPT * (OO + 1); o += 256) outrow[o] = 0.0f;
        return;  // uniform: all threads exit, no barrier mismatch
    }

    // ================= KNN: wave w selects 16 neighbors of point i0+w ======
    const int i = i0 + w;
    const float cix = xb[i * XCH + 0];
    const float ciy = xb[i * XCH + 1];

    const int j0 = lane, j1 = lane + 64;
    float d0, d1;
    {
        const float2 c0 = *(const float2*)(xb + j0 * XCH);
        const float m0 = xb[j0 * XCH + (XCH - 1)];
        float dx = cix - c0.x, dy = ciy - c0.y;
        d0 = __fadd_rn(__fmul_rn(dx, dx), __fmul_rn(dy, dy));
        if (m0 <= 0.0f || j0 == i) d0 = BIGD;
    }
    {
        const float2 c1 = *(const float2*)(xb + j1 * XCH);
        const float m1 = xb[j1 * XCH + (XCH - 1)];
        float dx = cix - c1.x, dy = ciy - c1.y;
        d1 = __fadd_rn(__fmul_rn(dx, dx), __fmul_rn(dy, dy));
        if (m1 <= 0.0f || j1 == i) d1 = BIGD;
    }

    const unsigned d0b = __float_as_uint(d0);
    const unsigned d1b = __float_as_uint(d1);

    unsigned long long A0 = ~0ull, A1 = ~0ull, W0 = 0ull, W1 = 0ull;
    int need = KK;

    // one refinement step: z* = candidates in A* whose current bit is 0
    auto step = [&](unsigned long long m0, unsigned long long m1) {
        const unsigned long long z0 = A0 & m0;
        const unsigned long long z1 = A1 & m1;
        const int c = __popcll(z0) + __popcll(z1);
        if (c == need) { W0 |= z0; W1 |= z1; A0 = A1 = 0ull; need = 0; }
        else if (c > need) { A0 = z0; A1 = z1; }
        else { W0 |= z0; W1 |= z1; need -= c; A0 &= ~z0; A1 &= ~z1; }
    };

    // phase A: distance bits 30..0 (bit 31 = sign = 0 always)
#pragma unroll 1
    for (int bp = 30; bp >= 0; --bp) {
        if (need == 0) break;
        const unsigned long long m0 = __ballot(((d0b >> bp) & 1u) == 0u);
        const unsigned long long m1 = __ballot(((d1b >> bp) & 1u) == 0u);
        step(m0, m1);
    }
    // phase B: index bits 6..0 (j0 = lane, j1 = lane+64): constant masks
    if (need) step(~0ull, 0ull);  // bit 6: all j0 are 0, all j1 are 1
    {
        const unsigned long long M5 = 0x00000000FFFFFFFFull;
        const unsigned long long M4 = 0x0000FFFF0000FFFFull;
        const unsigned long long M3 = 0x00FF00FF00FF00FFull;
        const unsigned long long M2 = 0x0F0F0F0F0F0F0F0Full;
        const unsigned long long M1 = 0x3333333333333333ull;
        const unsigned long long M0 = 0x5555555555555555ull;
        if (need) step(M5, M5);
        if (need) step(M4, M4);
        if (need) step(M3, M3);
        if (need) step(M2, M2);
        if (need) step(M1, M1);
        if (need) step(M0, M0);
    }
    W0 |= A0; W1 |= A1;  // keys unique => remaining actives are exactly the rest

    // compact winners into per-wave slots (same order as r4 -> identical sums)
    unsigned int mb0 = __builtin_amdgcn_mbcnt_lo((unsigned)(W0 & 0xffffffffull), 0u);
    mb0 = __builtin_amdgcn_mbcnt_hi((unsigned)(W0 >> 32), mb0);
    unsigned int mb1 = __builtin_amdgcn_mbcnt_lo((unsigned)(W1 & 0xffffffffull), 0u);
    mb1 = __builtin_amdgcn_mbcnt_hi((unsigned)(W1 >> 32), mb1);
    const int base1 = __popcll(W0);

    if ((W0 >> lane) & 1ull) sknn[w][mb0] = j0;
    if ((W1 >> lane) & 1ull) sknn[w][base1 + mb1] = j1;
    __syncthreads();

    // ================= edge build -> GEMM1 B-fragment (registers only) =====
    // this thread: point g=w, neighbor slot lcol, channel block quad (8 ch)
    const int jn = sknn[w][lcol];
    const float* ci = xb + i * XCH;
    const float* cj = xb + jn * XCH;
    // rows are 40 B apart -> 8 B aligned: use float2 loads
    const float2 a01 = *(const float2*)(ci + 0);
    const float2 a23 = *(const float2*)(ci + 2);
    const float2 a45 = *(const float2*)(ci + 4);
    const float2 a67 = *(const float2*)(ci + 6);
    const float  a8  = ci[8];
    const float2 n01 = *(const float2*)(cj + 0);
    const float2 n23 = *(const float2*)(cj + 2);
    const float2 n45 = *(const float2*)(cj + 4);
    const float2 n67 = *(const float2*)(cj + 6);
    const float  n8  = cj[8];

    float v[8];
#pragma unroll
    for (int e = 0; e < 8; ++e) v[e] = 0.0f;
    if (quad == 0) {           // channels 0..7 = center ch 0..7
        v[0] = a01.x; v[1] = a01.y; v[2] = a23.x; v[3] = a23.y;
        v[4] = a45.x; v[5] = a45.y; v[6] = a67.x; v[7] = a67.y;
    } else if (quad == 1) {    // ch 8 = center ch8; ch 9..15 = diff ch 0..6
        v[0] = a8;
        v[1] = n01.x - a01.x; v[2] = n01.y - a01.y;
        v[3] = n23.x - a23.x; v[4] = n23.y - a23.y;
        v[5] = n45.x - a45.x; v[6] = n45.y - a45.y;
        v[7] = n67.x - a67.x;
    } else if (quad == 2) {    // ch 16 = diff ch7; ch 17 = diff ch8; rest 0
        v[0] = n67.y - a67.y;
        v[1] = n8 - a8;
    }                          // quad 3: zero padding (K 18 -> 32)

    bf16x8 ef;
#pragma unroll
    for (int e = 0; e < 8; ++e) ef[e] = (__bf16)v[e];

    // ---- GEMM1 (MFMA): h1^T tiles; A = W1p frags (global/L2), B = ef ----
    bf16x8 wf[8];
#pragma unroll
    for (int nt = 0; nt < 8; ++nt)
        wf[nt] = *(const bf16x8*)&W1p[(size_t)((nt * 64 + lane) * 8)];

    const f32x4 z4 = {0.0f, 0.0f, 0.0f, 0.0f};
    f32x4 h[8];
#pragma unroll
    for (int nt = 0; nt < 8; ++nt)
        h[nt] = __builtin_amdgcn_mfma_f32_16x16x32_bf16(wf[nt], ef, z4, 0, 0, 0);

    // ---- epilogue 1: relu(+b1), write bf16 into GEMM2 A-frag order ----
    // C layout: col = lcol = edge row (within tile w), row = quad*4+r = h1
    // feature m = GEMM2's k. 4 consecutive k per (nt,quad) -> one b64 write.
#pragma unroll
    for (int nt = 0; nt < 8; ++nt) {
        const int ks = nt >> 1;
        const int lp = (((nt * 2 + (quad >> 1)) & 3) << 4) | lcol;
        bf16x4 hv;
#pragma unroll
        for (int r = 0; r < 4; ++r) {
            const int m = nt * 16 + quad * 4 + r;
            hv[r] = (__bf16)fmaxf(h[nt][r] + sb1[m], 0.0f);
        }
        *(bf16x4*)&sh1A[((ks * 4 + w) * 64 + lp) * 8 + (quad & 1) * 4] = hv;
    }
    __syncthreads();

    // ---- GEMM2 (MFMA): h2[64][256] = relu(h1 @ W2 + b2), fused K-mean ----
    f32x4 acc[GPT][4];
#pragma unroll
    for (int g = 0; g < GPT; ++g)
#pragma unroll
        for (int ct = 0; ct < 4; ++ct) acc[g][ct] = z4;

#pragma unroll
    for (int ks = 0; ks < 4; ++ks) {
        bf16x8 af[GPT], bfr[4];
#pragma unroll
        for (int g = 0; g < GPT; ++g)
            af[g] = *(const bf16x8*)&sh1A[((ks * 4 + g) * 64 + lane) * 8];
#pragma unroll
        for (int ct = 0; ct < 4; ++ct)
            bfr[ct] = *(const bf16x8*)&W2p[(size_t)((((w * 4 + ct) * 4 + ks) * 64 + lane) * 8)];
#pragma unroll
        for (int g = 0; g < GPT; ++g)
#pragma unroll
            for (int ct = 0; ct < 4; ++ct)
                acc[g][ct] = __builtin_amdgcn_mfma_f32_16x16x32_bf16(
                    af[g], bfr[ct], acc[g][ct], 0, 0, 0);
    }

    // ---- epilogue 2: relu(+b2), K-sum = tile column sum via shuffles ----
    // C layout: col=lcol, row=quad*4+r; tile g's 16 rows = point g's K
    // neighbors. Partial over 4 rows in-lane, then fold quads (xor 16, 32).
    float val[4];
#pragma unroll
    for (int g = 0; g < GPT; ++g) {
#pragma unroll
        for (int ct = 0; ct < 4; ++ct) {
            const int col = w * 64 + ct * 16 + lcol;
            const float bc = sb2[col];
            float s = 0.0f;
#pragma unroll
            for (int r = 0; r < 4; ++r) s += fmaxf(acc[g][ct][r] + bc, 0.0f);
            s += __shfl_xor(s, 16, 64);
            s += __shfl_xor(s, 32, 64);
            if (quad == g) val[ct] = s;   // lane (quad=g, lcol) keeps point g
        }
    }
    const float m = smask[quad] * (1.0f / KK);
#pragma unroll
    for (int ct = 0; ct < 4; ++ct)
        outrow[(size_t)quad * (OO + 1) + w * 64 + ct * 16 + lcol] = val[ct] * m;
    if (tid < GPT) outrow[(size_t)tid * (OO + 1) + OO] = smask[tid];  // ones ch * mask
}

extern "C" void kernel_launch(void* const* d_in, const int* in_sizes, int n_in,
                              void* d_out, int out_size, void* d_ws, size_t ws_size,
                              hipStream_t stream) {
    const float* x  = (const float*)d_in[0];
    const float* W1 = (const float*)d_in[1];
    const float* b1 = (const float*)d_in[2];
    const float* W2 = (const float*)d_in[3];
    const float* b2 = (const float*)d_in[4];
    float* out = (float*)d_out;

    __bf16* W2p = (__bf16*)d_ws;                    // 64 KB
    __bf16* W1p = (__bf16*)((char*)d_ws + 65536);   // 8 KB

    pack_w_kernel<<<144, 256, 0, stream>>>(W1, W2, W2p, W1p);

    const int nblocks = (BB * PP) / GPT;  // 8192
    mlp_kernel<<<nblocks, 256, 0, stream>>>(x, W1p, b1, W2p, b2, out);
}